// Round 2
// baseline (1144.120 us; speedup 1.0000x reference)
//
#include <hip/hip_runtime.h>
#include <hip/hip_bf16.h>
#include <hip/hip_fp16.h>
#include <math.h>

#define N_NODES 100000
#define IN_DIM 64
#define EMBED_DIM 128
#define EDGE_DIM 32
#define N_EDGES 1600000

typedef __attribute__((ext_vector_type(8))) short bf16x8;
typedef __attribute__((ext_vector_type(4))) float f32x4;

__device__ __forceinline__ ushort f2bf(float f) {
    union { float f; uint i; } v; v.f = f;
    uint x = v.i;
    return (ushort)((x + 0x7fffu + ((x >> 16) & 1u)) >> 16);  // RNE
}

// ---------------------------------------------------------------------------
// x -> f16 (halves gather footprint; L3-resident node features)
// ---------------------------------------------------------------------------
__global__ __launch_bounds__(256) void cvt_x_kernel(
    const float* __restrict__ x, __half* __restrict__ xh)
{
    const int i = blockIdx.x * blockDim.x + threadIdx.x;
    if (i < N_NODES * IN_DIM / 4) {
        float4 v = ((const float4*)x)[i];
        ((__half2*)xh)[2 * i]     = __floats2half2_rn(v.x, v.y);
        ((__half2*)xh)[2 * i + 1] = __floats2half2_rn(v.z, v.w);
    }
}

// ---------------------------------------------------------------------------
// ea -> bf16 (one 64B line per edge row; random gathers in agg become 1 line)
// ---------------------------------------------------------------------------
__global__ __launch_bounds__(256) void cvt_ea_kernel(
    const float* __restrict__ ea, ushort* __restrict__ eab)
{
    const int i = blockIdx.x * blockDim.x + threadIdx.x;
    if (i < N_EDGES * EDGE_DIM / 4) {
        float4 v = ((const float4*)ea)[i];
        ushort4 o;
        o.x = f2bf(v.x); o.y = f2bf(v.y); o.z = f2bf(v.z); o.w = f2bf(v.w);
        ((ushort4*)eab)[i] = o;
    }
}

// ---------------------------------------------------------------------------
// CSR build: histogram -> exclusive scan -> scatter (packed {eid, other})
// ---------------------------------------------------------------------------
__global__ __launch_bounds__(256) void hist_kernel(
    const int* __restrict__ ei, int* __restrict__ deg_in, int* __restrict__ deg_out)
{
    const int e = blockIdx.x * blockDim.x + threadIdx.x;
    if (e < N_EDGES) {
        const int s = ei[e];
        const int d = ei[N_EDGES + e];
        atomicAdd(deg_in + d, 1);
        atomicAdd(deg_out + s, 1);
    }
}

__global__ __launch_bounds__(256) void scan_kernel(
    const int* __restrict__ deg_in,  int* __restrict__ start_in,  int* __restrict__ pos_in,
    const int* __restrict__ deg_out, int* __restrict__ start_out, int* __restrict__ pos_out)
{
    const int* deg = blockIdx.x ? deg_out : deg_in;
    int* start     = blockIdx.x ? start_out : start_in;
    int* pos       = blockIdx.x ? pos_out   : pos_in;
    const int t = threadIdx.x;
    const int C = (N_NODES + 255) / 256;   // 391
    const int b0 = t * C;
    int s = 0;
    for (int k = 0; k < C; ++k) {
        const int idx = b0 + k;
        if (idx < N_NODES) s += deg[idx];
    }
    __shared__ int sc[256];
    sc[t] = s;
    __syncthreads();
    for (int o = 1; o < 256; o <<= 1) {
        const int v = (t >= o) ? sc[t - o] : 0;
        __syncthreads();
        sc[t] += v;
        __syncthreads();
    }
    int ex = sc[t] - s;                    // exclusive prefix for this thread
    for (int k = 0; k < C; ++k) {
        const int idx = b0 + k;
        if (idx < N_NODES) {
            const int d = deg[idx];
            start[idx] = ex;
            pos[idx]   = ex;
            ex += d;
        }
    }
}

__global__ __launch_bounds__(256) void scatter_kernel(
    const int* __restrict__ ei,
    int* __restrict__ pos_in, int* __restrict__ pos_out,
    int2* __restrict__ perm_in, int2* __restrict__ perm_out)
{
    const int e = blockIdx.x * blockDim.x + threadIdx.x;
    if (e < N_EDGES) {
        const int s = ei[e];
        const int d = ei[N_EDGES + e];
        const int p = atomicAdd(pos_in + d, 1);
        perm_in[p] = make_int2(e, s);       // in-dir: aggregate at dst, gather x[src]
        const int q = atomicAdd(pos_out + s, 1);
        perm_out[q] = make_int2(e, d);      // out-dir: aggregate at src, gather x[dst]
    }
}

// ---------------------------------------------------------------------------
// CSR aggregation: one wave per node (contiguous ranges), 16 edges per MFMA
// chunk, f32 register accumulation, single coalesced row store. No atomics.
// A[m=r][k=h*8+j] = ea_b[perm[c0+r].x], B = We with permuted cols
// cp(t,r)=(t>>1)*32+2r+(t&1); C/D row = h*4+i, col = cp(t,r).
// ---------------------------------------------------------------------------
__global__ __launch_bounds__(256) void agg_kernel(
    const __half* __restrict__ xh, const ushort* __restrict__ eab,
    const float* __restrict__ We_in, const float* __restrict__ be_in,
    const float* __restrict__ We_out, const float* __restrict__ be_out,
    const int* __restrict__ start_in, const int* __restrict__ deg_in,
    const int2* __restrict__ perm_in,
    const int* __restrict__ start_out, const int* __restrict__ deg_out,
    const int2* __restrict__ perm_out,
    float* __restrict__ agg_in, float* __restrict__ agg_out)
{
    const int lane = threadIdx.x & 63;
    const int r = lane & 15;
    const int h = lane >> 4;
    const int wave = threadIdx.x >> 6;

    const bool dirOut = blockIdx.x >= 2048;
    const float* We   = dirOut ? We_out : We_in;
    const float* be   = dirOut ? be_out : be_in;
    const int* start  = dirOut ? start_out : start_in;
    const int* deg    = dirOut ? deg_out : deg_in;
    const int2* perm  = dirOut ? perm_out : perm_in;
    float* agg        = dirOut ? agg_out : agg_in;

    // Preload B fragments (permuted cols) + bias
    bf16x8 bW[4];
    float beV[4];
#pragma unroll
    for (int t = 0; t < 4; ++t) {
        const int cp = ((t >> 1) << 5) + (r << 1) + (t & 1);
        const float* p = We + (h * 8) * 64 + cp;
        bf16x8 bv;
#pragma unroll
        for (int j = 0; j < 8; ++j) bv[j] = (short)f2bf(p[j * 64]);
        bW[t] = bv;
        beV[t] = be[cp];
    }

    const int wid = (blockIdx.x & 2047) * 4 + wave;       // 0..8191 per direction
    const int NPW = (N_NODES + 8191) / 8192;              // 13 nodes per wave
    const int n0 = wid * NPW;
    const int n1 = min(N_NODES, n0 + NPW);

    for (int n = n0; n < n1; ++n) {
        const int st = start[n];
        const int en = st + deg[n];
        float accL[4] = {0.f, 0.f, 0.f, 0.f};

        for (int c0 = st; c0 < en; c0 += 16) {
            const int slot = c0 + r;
            const int2 pe = perm[slot < en ? slot : en - 1];
            // A fragment: one 16B load; 4 h-quarters share the edge's 64B line
            const bf16x8 a = *(const bf16x8*)(eab + (size_t)pe.x * 32 + h * 8);

            f32x4 C[4];
#pragma unroll
            for (int t = 0; t < 4; ++t) {
                f32x4 z = {0.f, 0.f, 0.f, 0.f};
                C[t] = __builtin_amdgcn_mfma_f32_16x16x32_bf16(a, bW[t], z, 0, 0, 0);
            }

            const int rem = en - c0;
            const int ownOther = pe.y;
#pragma unroll
            for (int i = 0; i < 4; ++i) {
                const int m = h * 4 + i;
                const int other = __shfl(ownOther, m, 64);
                const bool valid = m < rem;
#pragma unroll
                for (int tp = 0; tp < 2; ++tp) {
                    const __half2 xs =
                        *(const __half2*)(xh + (size_t)other * 64 + 32 * tp + 2 * r);
                    float m0 = fmaxf(__low2float(xs)  + C[2 * tp][i]     + beV[2 * tp],     0.f);
                    float m1 = fmaxf(__high2float(xs) + C[2 * tp + 1][i] + beV[2 * tp + 1], 0.f);
                    if (valid) {
                        accL[2 * tp]     += m0;
                        accL[2 * tp + 1] += m1;
                    }
                }
            }
        }

        // Reduce over the 4 h-quarters (rows) -> per-col totals on all lanes
#pragma unroll
        for (int t = 0; t < 4; ++t) {
            accL[t] += __shfl_xor(accL[t], 16, 64);
            accL[t] += __shfl_xor(accL[t], 32, 64);
        }
        if (h < 2) {
            float2 v = make_float2(accL[2 * h], accL[2 * h + 1]);
            *(float2*)(agg + (size_t)n * 64 + 32 * h + 2 * r) = v;
        }
    }
}

// ---------------------------------------------------------------------------
// Fallback edge stage (round-1 f16-atomic version) for small workspaces.
// ---------------------------------------------------------------------------
__global__ __launch_bounds__(256) void edge_kernel(
    const __half* __restrict__ xh, const int* __restrict__ ei,
    const float* __restrict__ ea,
    const float* __restrict__ We_in, const float* __restrict__ be_in,
    const float* __restrict__ We_out, const float* __restrict__ be_out,
    __half* __restrict__ agg_in, __half* __restrict__ agg_out)
{
    const int lane = threadIdx.x & 63;
    const int r = lane & 15;
    const int h = lane >> 4;
    const int wave = threadIdx.x >> 6;

    bf16x8 bIn[4], bOut[4];
    float beI[4], beO[4];
#pragma unroll
    for (int t = 0; t < 4; ++t) {
        const int cp = ((t >> 1) << 5) + (r << 1) + (t & 1);
        const float* p1 = We_in  + (h * 8) * 64 + cp;
        const float* p2 = We_out + (h * 8) * 64 + cp;
        bf16x8 b1v, b2v;
#pragma unroll
        for (int j = 0; j < 8; ++j) {
            b1v[j] = (short)f2bf(p1[j * 64]);
            b2v[j] = (short)f2bf(p2[j * 64]);
        }
        bIn[t] = b1v; bOut[t] = b2v;
        beI[t] = be_in[cp];
        beO[t] = be_out[cp];
    }

    const int nGroups = N_EDGES / 16;
    const int stride = gridDim.x * 4;
    for (int g = blockIdx.x * 4 + wave; g < nGroups; g += stride) {
        const int e0 = g * 16;
        const float* ap = ea + (size_t)(e0 + r) * 32 + h * 8;
        float4 av0 = *(const float4*)ap;
        float4 av1 = *(const float4*)(ap + 4);
        bf16x8 a;
        a[0] = (short)f2bf(av0.x); a[1] = (short)f2bf(av0.y);
        a[2] = (short)f2bf(av0.z); a[3] = (short)f2bf(av0.w);
        a[4] = (short)f2bf(av1.x); a[5] = (short)f2bf(av1.y);
        a[6] = (short)f2bf(av1.z); a[7] = (short)f2bf(av1.w);

        f32x4 cIn[4], cOut[4];
#pragma unroll
        for (int t = 0; t < 4; ++t) {
            f32x4 z = {0.f, 0.f, 0.f, 0.f};
            cIn[t]  = __builtin_amdgcn_mfma_f32_16x16x32_bf16(a, bIn[t],  z, 0, 0, 0);
            cOut[t] = __builtin_amdgcn_mfma_f32_16x16x32_bf16(a, bOut[t], z, 0, 0, 0);
        }

        const int4 s4 = *(const int4*)(ei + e0 + h * 4);
        const int4 d4 = *(const int4*)(ei + N_EDGES + e0 + h * 4);
        const int ss[4] = {s4.x, s4.y, s4.z, s4.w};
        const int dd[4] = {d4.x, d4.y, d4.z, d4.w};

#pragma unroll
        for (int i = 0; i < 4; ++i) {
            const int s = ss[i];
            const int d = dd[i];
#pragma unroll
            for (int tp = 0; tp < 2; ++tp) {
                const int coff = 32 * tp + 2 * r;
                __half2 xs = *(const __half2*)(xh + (size_t)s * 64 + coff);
                float m0 = fmaxf(__low2float(xs)  + cIn[2 * tp][i]     + beI[2 * tp],     0.0f);
                float m1 = fmaxf(__high2float(xs) + cIn[2 * tp + 1][i] + beI[2 * tp + 1], 0.0f);
                if (m0 != 0.0f || m1 != 0.0f)
                    unsafeAtomicAdd((__half2*)(agg_in + (size_t)d * 64 + coff),
                                    __floats2half2_rn(m0, m1));
                __half2 xd = *(const __half2*)(xh + (size_t)d * 64 + coff);
                float n0 = fmaxf(__low2float(xd)  + cOut[2 * tp][i]     + beO[2 * tp],     0.0f);
                float n1 = fmaxf(__high2float(xd) + cOut[2 * tp + 1][i] + beO[2 * tp + 1], 0.0f);
                if (n0 != 0.0f || n1 != 0.0f)
                    unsafeAtomicAdd((__half2*)(agg_out + (size_t)s * 64 + coff),
                                    __floats2half2_rn(n0, n1));
            }
        }
    }
}

// ---------------------------------------------------------------------------
// Node stage (templated on agg dtype: f32 for CSR path, f16 for fallback)
// ---------------------------------------------------------------------------
#define T_STRIDE 136

__device__ __forceinline__ void load8f(const float* __restrict__ p, float* o) {
    float4 a = *(const float4*)p;
    float4 b = *(const float4*)(p + 4);
    o[0] = a.x; o[1] = a.y; o[2] = a.z; o[3] = a.w;
    o[4] = b.x; o[5] = b.y; o[6] = b.z; o[7] = b.w;
}
__device__ __forceinline__ void load8f(const __half* __restrict__ p, float* o) {
#pragma unroll
    for (int j = 0; j < 4; ++j) {
        __half2 g = *(const __half2*)(p + 2 * j);
        o[2 * j]     = __low2float(g);
        o[2 * j + 1] = __high2float(g);
    }
}

template<typename AggT>
__device__ __forceinline__ void gine_mlp(
    const float* __restrict__ x, const AggT* __restrict__ agg,
    const float* __restrict__ W1, const float* __restrict__ b1,
    const float* __restrict__ W2,
    int n0, int r, int h, ushort* Tw, f32x4 hAcc[8])
{
    bf16x8 a0[2];
#pragma unroll
    for (int half_ = 0; half_ < 2; ++half_) {
        const int kb = half_ * 32 + h * 8;
        float xv[8], gv[8];
        load8f(x   + (size_t)(n0 + r) * 64 + kb, xv);
        load8f(agg + (size_t)(n0 + r) * 64 + kb, gv);
        bf16x8 v;
#pragma unroll
        for (int j = 0; j < 8; ++j) v[j] = (short)f2bf(xv[j] + gv[j]);
        a0[half_] = v;
    }

    __threadfence_block();

    // Layer 1: T = gelu(H0 @ W1 + b1) -> LDS (bf16)
#pragma unroll
    for (int t = 0; t < 8; ++t) {
        const float* w1p = W1 + (h * 8) * 128 + 16 * t + r;
        bf16x8 b0v, b1v;
#pragma unroll
        for (int j = 0; j < 8; ++j) {
            b0v[j] = (short)f2bf(w1p[j * 128]);
            b1v[j] = (short)f2bf(w1p[4096 + j * 128]);
        }
        f32x4 acc = {0.f, 0.f, 0.f, 0.f};
        acc = __builtin_amdgcn_mfma_f32_16x16x32_bf16(a0[0], b0v, acc, 0, 0, 0);
        acc = __builtin_amdgcn_mfma_f32_16x16x32_bf16(a0[1], b1v, acc, 0, 0, 0);
        float bias = b1[16 * t + r];
#pragma unroll
        for (int i = 0; i < 4; ++i) {
            float v = acc[i] + bias;
            float g = 0.5f * v * (1.0f + erff(v * 0.70710678118654752f));
            Tw[(h * 4 + i) * T_STRIDE + 16 * t + r] = f2bf(g);
        }
    }

    __threadfence_block();

    // Layer 2: h = T @ W2
    bf16x8 aT[4];
#pragma unroll
    for (int ks = 0; ks < 4; ++ks)
        aT[ks] = *(const bf16x8*)(Tw + r * T_STRIDE + ks * 32 + h * 8);
#pragma unroll
    for (int t = 0; t < 8; ++t) {
        const float* w2p = W2 + (h * 8) * 128 + 16 * t + r;
        f32x4 acc = {0.f, 0.f, 0.f, 0.f};
#pragma unroll
        for (int ks = 0; ks < 4; ++ks) {
            bf16x8 bv;
#pragma unroll
            for (int j = 0; j < 8; ++j) bv[j] = (short)f2bf(w2p[(ks * 32 + j) * 128]);
            acc = __builtin_amdgcn_mfma_f32_16x16x32_bf16(aT[ks], bv, acc, 0, 0, 0);
        }
        hAcc[t] = acc;
    }
}

template<typename AggT>
__global__ __launch_bounds__(256) void node_kernel(
    const float* __restrict__ x,
    const AggT* __restrict__ agg_in, const AggT* __restrict__ agg_out,
    const float* __restrict__ W1_in, const float* __restrict__ b1_in,
    const float* __restrict__ W2_in, const float* __restrict__ b2_in,
    const float* __restrict__ W1_out, const float* __restrict__ b1_out,
    const float* __restrict__ W2_out, const float* __restrict__ b2_out,
    const float* __restrict__ Wr, const float* __restrict__ br,
    float* __restrict__ out)
{
    const int lane = threadIdx.x & 63;
    const int r = lane & 15;
    const int h = lane >> 4;
    const int wave = threadIdx.x >> 6;

    __shared__ __align__(16) ushort Tld[4][16 * T_STRIDE];
    ushort* Tw = &Tld[wave][0];

    const int g = blockIdx.x * 4 + wave;
    if (g >= N_NODES / 16) return;
    const int n0 = g * 16;

    f32x4 hIn[8], hOut[8];
    gine_mlp(x, agg_in,  W1_in,  b1_in,  W2_in,  n0, r, h, Tw, hIn);
    gine_mlp(x, agg_out, W1_out, b1_out, W2_out, n0, r, h, Tw, hOut);

    bf16x8 ar[2];
#pragma unroll
    for (int half_ = 0; half_ < 2; ++half_) {
        const float* xp = x + (size_t)(n0 + r) * 64 + half_ * 32 + h * 8;
        bf16x8 v;
#pragma unroll
        for (int j = 0; j < 8; ++j) v[j] = (short)f2bf(xp[j]);
        ar[half_] = v;
    }

#pragma unroll
    for (int t = 0; t < 8; ++t) {
        const float* wrp = Wr + (h * 8) * 128 + 16 * t + r;
        bf16x8 b0v, b1v;
#pragma unroll
        for (int j = 0; j < 8; ++j) {
            b0v[j] = (short)f2bf(wrp[j * 128]);
            b1v[j] = (short)f2bf(wrp[4096 + j * 128]);
        }
        f32x4 rt = {0.f, 0.f, 0.f, 0.f};
        rt = __builtin_amdgcn_mfma_f32_16x16x32_bf16(ar[0], b0v, rt, 0, 0, 0);
        rt = __builtin_amdgcn_mfma_f32_16x16x32_bf16(ar[1], b1v, rt, 0, 0, 0);

        const int c = 16 * t + r;
        float b2i = b2_in[c];
        float b2o = b2_out[c];
        float brv = br[c];
#pragma unroll
        for (int i = 0; i < 4; ++i) {
            float o = 0.5f * (hOut[t][i] + b2o) + 0.5f * (hIn[t][i] + b2i) + rt[i] + brv;
            out[(size_t)(n0 + h * 4 + i) * 128 + c] = o;
        }
    }
}

extern "C" void kernel_launch(void* const* d_in, const int* in_sizes, int n_in,
                              void* d_out, int out_size, void* d_ws, size_t ws_size,
                              hipStream_t stream) {
    const float* x      = (const float*)d_in[0];
    const int*   ei     = (const int*)d_in[1];
    const float* ea     = (const float*)d_in[2];
    const float* We_in  = (const float*)d_in[3];
    const float* be_in  = (const float*)d_in[4];
    const float* W1_in  = (const float*)d_in[5];
    const float* b1_in  = (const float*)d_in[6];
    const float* W2_in  = (const float*)d_in[7];
    const float* b2_in  = (const float*)d_in[8];
    const float* We_out = (const float*)d_in[9];
    const float* be_out = (const float*)d_in[10];
    const float* W1_out = (const float*)d_in[11];
    const float* b1_out = (const float*)d_in[12];
    const float* W2_out = (const float*)d_in[13];
    const float* b2_out = (const float*)d_in[14];
    const float* Wr     = (const float*)d_in[15];
    const float* br     = (const float*)d_in[16];

    // CSR-path workspace layout (all offsets 16B-aligned)
    const size_t EAB_B   = (size_t)N_EDGES * EDGE_DIM * 2;     // 102,400,000
    const size_t XH_B    = (size_t)N_NODES * IN_DIM * 2;       //  12,800,000
    const size_t AGG_B   = (size_t)N_NODES * IN_DIM * 4;       //  25,600,000
    const size_t PERM_B  = (size_t)N_EDGES * 8;                //  12,800,000
    const size_t META_B  = (size_t)N_NODES * 4;                //     400,000
    const size_t NEED    = EAB_B + XH_B + 2 * AGG_B + 2 * PERM_B + 6 * META_B;

    if (ws_size >= NEED) {
        char* w = (char*)d_ws;
        ushort* eab     = (ushort*)w;                    w += EAB_B;
        __half* xh      = (__half*)w;                    w += XH_B;
        float* agg_in   = (float*)w;                     w += AGG_B;
        float* agg_out  = (float*)w;                     w += AGG_B;
        int2* perm_in   = (int2*)w;                      w += PERM_B;
        int2* perm_out  = (int2*)w;                      w += PERM_B;
        int* deg_in     = (int*)w;                       w += META_B;
        int* deg_out    = (int*)w;                       w += META_B;
        int* start_in   = (int*)w;                       w += META_B;
        int* start_out  = (int*)w;                       w += META_B;
        int* pos_in     = (int*)w;                       w += META_B;
        int* pos_out    = (int*)w;

        hipMemsetAsync(deg_in, 0, 2 * META_B, stream);   // deg_in + deg_out

        cvt_x_kernel<<<(N_NODES * IN_DIM / 4 + 255) / 256, 256, 0, stream>>>(x, xh);
        cvt_ea_kernel<<<(N_EDGES * EDGE_DIM / 4 + 255) / 256, 256, 0, stream>>>(ea, eab);
        hist_kernel<<<(N_EDGES + 255) / 256, 256, 0, stream>>>(ei, deg_in, deg_out);
        scan_kernel<<<2, 256, 0, stream>>>(deg_in, start_in, pos_in,
                                           deg_out, start_out, pos_out);
        scatter_kernel<<<(N_EDGES + 255) / 256, 256, 0, stream>>>(
            ei, pos_in, pos_out, perm_in, perm_out);
        agg_kernel<<<4096, 256, 0, stream>>>(
            xh, eab, We_in, be_in, We_out, be_out,
            start_in, deg_in, perm_in, start_out, deg_out, perm_out,
            agg_in, agg_out);
        node_kernel<float><<<(N_NODES / 16 + 3) / 4, 256, 0, stream>>>(
            x, agg_in, agg_out,
            W1_in, b1_in, W2_in, b2_in,
            W1_out, b1_out, W2_out, b2_out,
            Wr, br, (float*)d_out);
    } else {
        // Fallback: round-1 f16-atomic path (38.4 MB workspace)
        __half* agg_in  = (__half*)d_ws;
        __half* agg_out = agg_in + (size_t)N_NODES * IN_DIM;
        __half* xh      = agg_out + (size_t)N_NODES * IN_DIM;
        const size_t agg_bytes = (size_t)2 * N_NODES * IN_DIM * sizeof(__half);

        hipMemsetAsync(d_ws, 0, agg_bytes, stream);
        cvt_x_kernel<<<(N_NODES * IN_DIM / 4 + 255) / 256, 256, 0, stream>>>(x, xh);
        edge_kernel<<<2048, 256, 0, stream>>>(xh, ei, ea, We_in, be_in, We_out, be_out,
                                              agg_in, agg_out);
        node_kernel<__half><<<(N_NODES / 16 + 3) / 4, 256, 0, stream>>>(
            x, agg_in, agg_out,
            W1_in, b1_in, W2_in, b2_in,
            W1_out, b1_out, W2_out, b2_out,
            Wr, br, (float*)d_out);
    }
}